// Round 8
// baseline (145.415 us; speedup 1.0000x reference)
//
#include <hip/hip_runtime.h>
#include <math.h>

#define TT 2048
#define HH 128
#define ROWS 8
#define SP 132   // row-major LDS stride (qs, os)
#define XR 144   // chunk-padded LDS row stride: 4 chunks x 36
#define NBLK (TT / ROWS)

__device__ __forceinline__ float dot4(float4 a, float4 b) {
    return a.x * b.x + a.y * b.y + a.z * b.z + a.w * b.w;
}

// chunk-padded x index: element k of row r lives at r*XR + (k>>5)*36 + (k&31)
__device__ __forceinline__ int xidx(int r, int k) {
    return r * XR + ((k >> 5) * 36) + (k & 31);
}

// ---- agent-scope (cross-XCD coherent, L1/L2-bypassing) accessors for kv/gi ----
__device__ __forceinline__ float2 load_f2_agent(const float* p) {
    unsigned long long u = __hip_atomic_load((const unsigned long long*)p,
                                             __ATOMIC_RELAXED, __HIP_MEMORY_SCOPE_AGENT);
    float2 r;
    r.x = __uint_as_float((unsigned)(u & 0xffffffffull));
    r.y = __uint_as_float((unsigned)(u >> 32));
    return r;
}
__device__ __forceinline__ float load_f_agent(const float* p) {
    return __hip_atomic_load(p, __ATOMIC_RELAXED, __HIP_MEMORY_SCOPE_AGENT);
}
__device__ __forceinline__ void store_f_agent(float* p, float v) {
    __hip_atomic_store(p, v, __ATOMIC_RELAXED, __HIP_MEMORY_SCOPE_AGENT);
}

// ---------------- prep: pack weights [k4][col] column-major + zero barrier ctrs ----
__global__ __launch_bounds__(256) void prep_kernel(
        const float* __restrict__ w_in, const float* __restrict__ w_out,
        const float* __restrict__ w_v, const float* __restrict__ w_q,
        const float* __restrict__ w_k, const float* __restrict__ w_o,
        const float* __restrict__ w_ff,
        float4* __restrict__ win_p, float4* __restrict__ wout_p,
        float4* __restrict__ wcat, float4* __restrict__ wff_p,
        unsigned* __restrict__ bar) {
    int i = blockIdx.x * 256 + threadIdx.x;
    if (blockIdx.x == 0 && threadIdx.x < 16) bar[threadIdx.x] = 0u;
    if (i < 4096) {
        int cg = i >> 7, col = i & 127;
        win_p[i] = ((const float4*)w_in)[col * 32 + cg];
    } else if (i < 8192) {
        int j = i - 4096, cg = j >> 7, col = j & 127;
        wout_p[j] = ((const float4*)w_out)[col * 32 + cg];
    } else if (i < 40960) {
        int j = i - 8192;
        int l = j >> 14, r = j & 16383, cg = r >> 9, col = r & 511;
        int sel = col >> 7, cm = col & 127;
        const float* s = (sel == 0 ? w_v : sel == 1 ? w_q : sel == 2 ? w_k : w_o) + l * HH * HH;
        wcat[j] = ((const float4*)s)[cm * 32 + cg];
    } else {
        int j = i - 40960;
        int l = j >> 13, r = j & 8191, cg = r >> 7, col = r & 127;
        const float* s = w_ff + l * HH * 256;
        wff_p[j] = ((const float4*)s)[col * 64 + cg];
    }
}

// ---- device-wide barrier WITHOUT agent fences (no L2 wb/inv — weights stay warm). ----
__device__ __forceinline__ void grid_barrier(unsigned* __restrict__ ctr) {
    __syncthreads();  // compiler emits s_waitcnt vmcnt(0) lgkmcnt(0) before s_barrier
    if (threadIdx.x == 0) {
        atomicAdd(ctr, 1u);  // device-scope atomic, coherent at L3
        while (__hip_atomic_load(ctr, __ATOMIC_RELAXED, __HIP_MEMORY_SCOPE_AGENT)
               < (unsigned)NBLK) {
            __builtin_amdgcn_s_sleep(8);
        }
    }
    __syncthreads();
}

// ---- async-stage a 128 KB panel (8192 float4) global -> LDS. Wave-uniform LDS base,
//      lane-consecutive global source (guide §5: dest = base + lane*16). ----
__device__ __forceinline__ void stage_wsh(const float4* __restrict__ src, float4* lds) {
    int tid = threadIdx.x;
    int wv = tid >> 6;
#pragma unroll
    for (int it = 0; it < 16; ++it) {
        __builtin_amdgcn_global_load_lds(
            (const __attribute__((address_space(1))) unsigned int*)(src + it * 512 + tid),
            (__attribute__((address_space(3))) unsigned int*)(lds + it * 512 + wv * 64),
            16, 0, 0);
    }
}

// ---- attention: wave wv owns row t0+wv; q,o from LDS; k,v,g,i via agent loads. ----
__device__ __forceinline__ void attn_row(int t0,
        const float* __restrict__ kb, const float* __restrict__ vb,
        const float* __restrict__ qs, const float* __restrict__ os,
        const float* __restrict__ g, const float* __restrict__ iexp,
        float* __restrict__ hs) {
    int tid = threadIdx.x;
    int wv = tid >> 6, lane = tid & 63;
    int t = t0 + wv;
    float2 q2 = *(const float2*)(qs + wv * SP + 2 * lane);
    float2 o2 = *(const float2*)(os + wv * SP + 2 * lane);
    int tp = t;
    float2 k2 = load_f2_agent(kb + tp * HH + 2 * lane);
    float2 v2 = load_f2_agent(vb + tp * HH + 2 * lane);
    float ie = load_f_agent(iexp + tp), gv = load_f_agent(g + tp);
    float nx = 0.f, ny = 0.f, dsum = 0.f, decay = 1.f;
    while (true) {
        bool cont = (tp > 0) && (gv != 0.f);
        float2 k2n = {0.f, 0.f}, v2n = {0.f, 0.f};
        float ien = 0.f, gvn = 0.f;
        if (cont) {  // prefetch next step; overlaps the reduce below
            k2n = load_f2_agent(kb + (tp - 1) * HH + 2 * lane);
            v2n = load_f2_agent(vb + (tp - 1) * HH + 2 * lane);
            ien = load_f_agent(iexp + tp - 1); gvn = load_f_agent(g + tp - 1);
        }
        float p = k2.x * q2.x + k2.y * q2.y;
#pragma unroll
        for (int off = 1; off <= 32; off <<= 1) p += __shfl_xor(p, off, 64);
        float coeff = decay * ie * p;
        nx += coeff * v2.x; ny += coeff * v2.y; dsum += coeff;
        if (!cont) break;
        decay *= gv;
        tp--; k2 = k2n; v2 = v2n; ie = ien; gv = gvn;
    }
    float inv = 1.f / fmaxf(fabsf(dsum), 1.f);
    int d = 2 * lane;
    *(float2*)(hs + wv * XR + (d >> 5) * 36 + (d & 31)) =
        make_float2(o2.x * nx * inv, o2.y * ny * inv);
}

// ---- f/i scalar gates: wave wv handles row wv; agent stores to g/iexp. ----
__device__ __forceinline__ void proj_fi(int t0, const float* __restrict__ xls,
        const float* __restrict__ w_f, const float* __restrict__ b_f,
        const float* __restrict__ w_i, const float* __restrict__ b_i,
        const int* __restrict__ start, float* __restrict__ g, float* __restrict__ iexp) {
    int tid = threadIdx.x;
    int wv = tid >> 6, lane = tid & 63;
    int d = 2 * lane;
    float2 xv = *(const float2*)(xls + wv * XR + (d >> 5) * 36 + (d & 31));
    float pf = xv.x * w_f[d] + xv.y * w_f[d + 1];
    float pi = xv.x * w_i[d] + xv.y * w_i[d + 1];
#pragma unroll
    for (int off = 1; off <= 32; off <<= 1) {
        pf += __shfl_xor(pf, off, 64);
        pi += __shfl_xor(pi, off, 64);
    }
    if (lane == 0) {
        int t = t0 + wv;
        store_f_agent(g + t, start[t] ? 0.f : 1.f / (1.f + expf(-(pf + b_f[0]))));
        store_f_agent(iexp + t, expf(pi + b_i[0]));
    }
}

// ---- 4 projections, NO-redundancy K-split: lane=(kc4,c16), cslot=wv*16+c (128 cols).
//      Each lane accumulates ALL 8 rows -> every weight float4 loaded once per block. ----
__device__ __forceinline__ void proj_block(int t0, const float* __restrict__ xls,
        const float4* __restrict__ wc,
        const float* __restrict__ b_v, const float* __restrict__ b_q,
        const float* __restrict__ b_k, const float* __restrict__ b_o,
        float* __restrict__ kb, float* __restrict__ vb,
        float* __restrict__ qs, float* __restrict__ os) {
    int tid = threadIdx.x;
    int lane = tid & 63, wv = tid >> 6;
    int kc = lane >> 4, c = lane & 15;
    int cslot = wv * 16 + c;
    float accv[8] = {}, accq[8] = {}, acck[8] = {}, acco[8] = {};
#pragma unroll
    for (int j = 0; j < 8; ++j) {
        const float4* wb = wc + (kc * 8 + j) * 512;
        float4 w0 = wb[cslot];
        float4 w1 = wb[128 + cslot];
        float4 w2 = wb[256 + cslot];
        float4 w3 = wb[384 + cslot];
#pragma unroll
        for (int rr = 0; rr < 8; ++rr) {
            float4 x4 = *(const float4*)(xls + rr * XR + kc * 36 + 4 * j);
            accv[rr] += dot4(x4, w0);
            accq[rr] += dot4(x4, w1);
            acck[rr] += dot4(x4, w2);
            acco[rr] += dot4(x4, w3);
        }
    }
#pragma unroll
    for (int rr = 0; rr < 8; ++rr) {
        accv[rr] += __shfl_xor(accv[rr], 16, 64); accv[rr] += __shfl_xor(accv[rr], 32, 64);
        accq[rr] += __shfl_xor(accq[rr], 16, 64); accq[rr] += __shfl_xor(accq[rr], 32, 64);
        acck[rr] += __shfl_xor(acck[rr], 16, 64); acck[rr] += __shfl_xor(acck[rr], 32, 64);
        acco[rr] += __shfl_xor(acco[rr], 16, 64); acco[rr] += __shfl_xor(acco[rr], 32, 64);
    }
    if (kc == 0) {
        const float ks = 0.088388347648318447f;  // 1/sqrt(128)
        float bv = b_v[cslot], bq = b_q[cslot], bk = b_k[cslot], bo = b_o[cslot];
#pragma unroll
        for (int rr = 0; rr < 8; ++rr) {
            int t = t0 + rr;
            store_f_agent(vb + t * HH + cslot, accv[rr] + bv);
            qs[rr * SP + cslot] = accq[rr] + bq;
            store_f_agent(kb + t * HH + cslot, acck[rr] * ks + bk);
            os[rr * SP + cslot] = 1.f / (1.f + expf(-(acco[rr] + bo)));
        }
    }
}

// ---- ff: z = lrelu([h, e] @ w_ff.T + b_ff); 8-way K-split, weights from LDS (wsh). ----
__device__ __forceinline__ void ff_block(const float* __restrict__ hsb,
        const float* __restrict__ esb, const float4* wffl,
        const float* __restrict__ b_ff, float* __restrict__ zs) {
    int tid = threadIdx.x;
    int lane = tid & 63, wv = tid >> 6;
    int kc = lane >> 3, c = lane & 7;
    int cslot = wv * 8 + c;  // 0..63, cols cslot and cslot+64
    const float* xb = (kc < 4) ? hsb : esb;
    int coff = (kc & 3) * 36;
    float a0[8] = {}, a1[8] = {};
#pragma unroll
    for (int j = 0; j < 8; ++j) {
        const float4* wl = wffl + (kc * 8 + j) * 128;
        float4 w0 = wl[cslot];
        float4 w1 = wl[64 + cslot];
#pragma unroll
        for (int rr = 0; rr < 8; ++rr) {
            float4 x4 = *(const float4*)(xb + rr * XR + coff + 4 * j);
            a0[rr] += dot4(x4, w0);
            a1[rr] += dot4(x4, w1);
        }
    }
#pragma unroll
    for (int rr = 0; rr < 8; ++rr) {
        a0[rr] += __shfl_xor(a0[rr], 8, 64); a0[rr] += __shfl_xor(a0[rr], 16, 64);
        a0[rr] += __shfl_xor(a0[rr], 32, 64);
        a1[rr] += __shfl_xor(a1[rr], 8, 64); a1[rr] += __shfl_xor(a1[rr], 16, 64);
        a1[rr] += __shfl_xor(a1[rr], 32, 64);
    }
    if (kc == 0) {
        float b0 = b_ff[cslot], b1 = b_ff[cslot + 64];
#pragma unroll
        for (int rr = 0; rr < 8; ++rr) {
            float z0 = a0[rr] + b0, z1 = a1[rr] + b1;
            z0 = z0 > 0.f ? z0 : 0.01f * z0;
            z1 = z1 > 0.f ? z1 : 0.01f * z1;
            zs[xidx(rr, cslot)] = z0;
            zs[xidx(rr, cslot + 64)] = z1;
        }
    }
}

// ---- 128->128 dense, 8-way K-split, no redundancy; ys (LDS) or yg (global). ----
__device__ __forceinline__ void dense128(int t0, const float* __restrict__ xls,
        const float4* __restrict__ Wp, const float* __restrict__ b,
        float* __restrict__ yg, float* __restrict__ ys) {
    int tid = threadIdx.x;
    int lane = tid & 63, wv = tid >> 6;
    int kc = lane >> 3, c = lane & 7;
    int cslot = wv * 8 + c;  // 0..63, cols cslot and cslot+64
    float a0[8] = {}, a1[8] = {};
#pragma unroll
    for (int j = 0; j < 4; ++j) {
        float4 w0 = Wp[(kc * 4 + j) * 128 + cslot];
        float4 w1 = Wp[(kc * 4 + j) * 128 + 64 + cslot];
        int off = (kc >> 1) * 36 + (kc & 1) * 16 + 4 * j;
#pragma unroll
        for (int rr = 0; rr < 8; ++rr) {
            float4 x4 = *(const float4*)(xls + rr * XR + off);
            a0[rr] += dot4(x4, w0);
            a1[rr] += dot4(x4, w1);
        }
    }
#pragma unroll
    for (int rr = 0; rr < 8; ++rr) {
        a0[rr] += __shfl_xor(a0[rr], 8, 64); a0[rr] += __shfl_xor(a0[rr], 16, 64);
        a0[rr] += __shfl_xor(a0[rr], 32, 64);
        a1[rr] += __shfl_xor(a1[rr], 8, 64); a1[rr] += __shfl_xor(a1[rr], 16, 64);
        a1[rr] += __shfl_xor(a1[rr], 32, 64);
    }
    if (kc == 0) {
        float b0 = b[cslot], b1 = b[cslot + 64];
#pragma unroll
        for (int rr = 0; rr < 8; ++rr) {
            float y0 = a0[rr] + b0, y1 = a1[rr] + b1;
            if (ys) { ys[xidx(rr, cslot)] = y0; ys[xidx(rr, cslot + 64)] = y1; }
            if (yg) {
                yg[(t0 + rr) * HH + cslot] = y0;
                yg[(t0 + rr) * HH + cslot + 64] = y1;
            }
        }
    }
}

// ---------------- fused: P0 | barrier | P1 | barrier | P2 ----------------
__global__ __launch_bounds__(512, 2) void mega_kernel(
        const float* __restrict__ emb, const int* __restrict__ start,
        const float4* __restrict__ win_p, const float* __restrict__ b_in,
        const float4* __restrict__ wcat,
        const float* __restrict__ b_v, const float* __restrict__ b_q,
        const float* __restrict__ b_k, const float* __restrict__ b_o,
        const float* __restrict__ w_f, const float* __restrict__ b_f,
        const float* __restrict__ w_i, const float* __restrict__ b_i,
        const float4* __restrict__ wff_p, const float* __restrict__ b_ff,
        const float4* __restrict__ wout_p, const float* __restrict__ b_out,
        float* __restrict__ k0b, float* __restrict__ v0b,
        float* __restrict__ k1b, float* __restrict__ v1b,
        float* __restrict__ g0, float* __restrict__ i0,
        float* __restrict__ g1, float* __restrict__ i1,
        unsigned* __restrict__ bar,
        float* __restrict__ out) {
    __shared__ float xs[ROWS * XR];
    __shared__ float es[ROWS * XR];
    __shared__ float hs[ROWS * XR];
    __shared__ float zs[ROWS * XR];
    __shared__ float qs[ROWS * SP];
    __shared__ float os[ROWS * SP];
    __shared__ float4 wsh[8192];  // 128 KB staged ff panel
    int tid = threadIdx.x;
    int t0 = blockIdx.x * ROWS;
    int wv = tid >> 6, lane = tid & 63;
    int d = 2 * lane;

    // ---- P0 ----
    float2 ev = *(const float2*)(emb + (t0 + wv) * HH + d);
    *(float2*)(xs + wv * XR + (d >> 5) * 36 + (d & 31)) = ev;
    __syncthreads();
    dense128(t0, xs, win_p, b_in, (float*)0, es);
    __syncthreads();
    proj_block(t0, es, wcat, b_v, b_q, b_k, b_o, k0b, v0b, qs, os);
    proj_fi(t0, es, w_f, b_f, w_i, b_i, start, g0, i0);
    grid_barrier(bar + 0);

    // ---- P1: stage wff0 under attn0 latency, then ff0 from LDS, proj1 ----
    stage_wsh(wff_p, wsh);
    attn_row(t0, k0b, v0b, qs, os, g0, i0, hs);
    __syncthreads();  // drains staging (vmcnt 0) + hs visible
    ff_block(hs, es, wsh, b_ff, zs);
    __syncthreads();
    proj_block(t0, zs, wcat + 16384, b_v + HH, b_q + HH, b_k + HH, b_o + HH,
               k1b, v1b, qs, os);
    proj_fi(t0, zs, w_f + HH, b_f + 1, w_i + HH, b_i + 1, start, g1, i1);
    grid_barrier(bar + 1);

    // ---- P2: stage wff1 under attn1, ff1 from LDS, final dense ----
    stage_wsh(wff_p + 8192, wsh);
    attn_row(t0, k1b, v1b, qs, os, g1, i1, hs);
    __syncthreads();
    ff_block(hs, es, wsh, b_ff + HH, zs);
    __syncthreads();
    dense128(t0, zs, wout_p, b_out, out, (float*)0);
}

extern "C" void kernel_launch(void* const* d_in, const int* in_sizes, int n_in,
                              void* d_out, int out_size, void* d_ws, size_t ws_size,
                              hipStream_t stream) {
    const float* emb   = (const float*)d_in[0];
    const int*   start = (const int*)  d_in[1];
    const float* w_in  = (const float*)d_in[2];
    const float* b_in  = (const float*)d_in[3];
    const float* w_out = (const float*)d_in[4];
    const float* b_out = (const float*)d_in[5];
    const float* w_f   = (const float*)d_in[6];
    const float* b_f   = (const float*)d_in[7];
    const float* w_i   = (const float*)d_in[8];
    const float* b_i   = (const float*)d_in[9];
    const float* w_v   = (const float*)d_in[10];
    const float* b_v   = (const float*)d_in[11];
    const float* w_q   = (const float*)d_in[12];
    const float* b_q   = (const float*)d_in[13];
    const float* w_k   = (const float*)d_in[14];
    const float* b_k   = (const float*)d_in[15];
    const float* w_o   = (const float*)d_in[16];
    const float* b_o   = (const float*)d_in[17];
    const float* w_ff  = (const float*)d_in[18];
    const float* b_ff  = (const float*)d_in[19];
    float* out = (float*)d_out;

    unsigned* bar = (unsigned*)d_ws;            // 16 counters, zeroed by prep
    float* ws = (float*)d_ws + 64;
    float* k0b = ws; ws += TT * HH;
    float* v0b = ws; ws += TT * HH;
    float* k1b = ws; ws += TT * HH;
    float* v1b = ws; ws += TT * HH;
    float* g0  = ws; ws += TT;
    float* i0  = ws; ws += TT;
    float* g1  = ws; ws += TT;
    float* i1  = ws; ws += TT;
    float4* win_p  = (float4*)ws; ws += 16384;   // 4096 float4
    float4* wout_p = (float4*)ws; ws += 16384;   // 4096 float4
    float4* wcat   = (float4*)ws; ws += 131072;  // 32768 float4 (2 layers)
    float4* wff_p  = (float4*)ws; ws += 65536;   // 16384 float4 (2 layers)

    prep_kernel<<<dim3(224), dim3(256), 0, stream>>>(
        w_in, w_out, w_v, w_q, w_k, w_o, w_ff, win_p, wout_p, wcat, wff_p, bar);
    mega_kernel<<<dim3(NBLK), dim3(512), 0, stream>>>(
        emb, start, win_p, b_in, wcat,
        b_v, b_q, b_k, b_o, w_f, b_f, w_i, b_i,
        wff_p, b_ff, wout_p, b_out,
        k0b, v0b, k1b, v1b, g0, i0, g1, i1,
        bar, out);
}

// Round 9
// 141.671 us; speedup vs baseline: 1.0264x; 1.0264x over previous
//
#include <hip/hip_runtime.h>
#include <math.h>

#define TT 2048
#define HH 128
#define ROWS 8
#define SP 132   // row-major LDS stride (qs, os)
#define XR 144   // chunk-padded LDS row stride: 4 chunks x 36
#define NBLK (TT / ROWS)

__device__ __forceinline__ float dot4(float4 a, float4 b) {
    return a.x * b.x + a.y * b.y + a.z * b.z + a.w * b.w;
}

// chunk-padded x index: element k of row r lives at r*XR + (k>>5)*36 + (k&31)
__device__ __forceinline__ int xidx(int r, int k) {
    return r * XR + ((k >> 5) * 36) + (k & 31);
}

// ---- agent-scope (cross-XCD coherent, L1/L2-bypassing) accessors for kv/gi ----
__device__ __forceinline__ float2 load_f2_agent(const float* p) {
    unsigned long long u = __hip_atomic_load((const unsigned long long*)p,
                                             __ATOMIC_RELAXED, __HIP_MEMORY_SCOPE_AGENT);
    float2 r;
    r.x = __uint_as_float((unsigned)(u & 0xffffffffull));
    r.y = __uint_as_float((unsigned)(u >> 32));
    return r;
}
__device__ __forceinline__ float load_f_agent(const float* p) {
    return __hip_atomic_load(p, __ATOMIC_RELAXED, __HIP_MEMORY_SCOPE_AGENT);
}
__device__ __forceinline__ void store_f_agent(float* p, float v) {
    __hip_atomic_store(p, v, __ATOMIC_RELAXED, __HIP_MEMORY_SCOPE_AGENT);
}

// ---------------- prep: pack weights [k4][col] column-major + zero barrier ctrs ----
__global__ __launch_bounds__(256) void prep_kernel(
        const float* __restrict__ w_in, const float* __restrict__ w_out,
        const float* __restrict__ w_v, const float* __restrict__ w_q,
        const float* __restrict__ w_k, const float* __restrict__ w_o,
        const float* __restrict__ w_ff,
        float4* __restrict__ win_p, float4* __restrict__ wout_p,
        float4* __restrict__ wcat, float4* __restrict__ wff_p,
        unsigned* __restrict__ bar) {
    int i = blockIdx.x * 256 + threadIdx.x;
    if (blockIdx.x == 0 && threadIdx.x < 16) bar[threadIdx.x] = 0u;
    if (i < 4096) {
        int cg = i >> 7, col = i & 127;
        win_p[i] = ((const float4*)w_in)[col * 32 + cg];
    } else if (i < 8192) {
        int j = i - 4096, cg = j >> 7, col = j & 127;
        wout_p[j] = ((const float4*)w_out)[col * 32 + cg];
    } else if (i < 40960) {
        int j = i - 8192;
        int l = j >> 14, r = j & 16383, cg = r >> 9, col = r & 511;
        int sel = col >> 7, cm = col & 127;
        const float* s = (sel == 0 ? w_v : sel == 1 ? w_q : sel == 2 ? w_k : w_o) + l * HH * HH;
        wcat[j] = ((const float4*)s)[cm * 32 + cg];
    } else {
        int j = i - 40960;
        int l = j >> 13, r = j & 8191, cg = r >> 7, col = r & 127;
        const float* s = w_ff + l * HH * 256;
        wff_p[j] = ((const float4*)s)[col * 64 + cg];
    }
}

// ---- device-wide barrier WITHOUT agent fences (no L2 wb/inv — weights stay warm). ----
__device__ __forceinline__ void grid_barrier(unsigned* __restrict__ ctr) {
    __syncthreads();  // compiler emits s_waitcnt vmcnt(0) lgkmcnt(0) before s_barrier
    if (threadIdx.x == 0) {
        atomicAdd(ctr, 1u);  // device-scope atomic, coherent at L3
        while (__hip_atomic_load(ctr, __ATOMIC_RELAXED, __HIP_MEMORY_SCOPE_AGENT)
               < (unsigned)NBLK) {
            __builtin_amdgcn_s_sleep(8);
        }
    }
    __syncthreads();
}

// ---- async-stage a 128 KB panel (8192 float4) global -> LDS (1024 threads). ----
__device__ __forceinline__ void stage_wsh(const float4* __restrict__ src, float4* lds) {
    int tid = threadIdx.x;
    int wv = tid >> 6;
#pragma unroll
    for (int it = 0; it < 8; ++it) {
        __builtin_amdgcn_global_load_lds(
            (const __attribute__((address_space(1))) unsigned int*)(src + it * 1024 + tid),
            (__attribute__((address_space(3))) unsigned int*)(lds + it * 1024 + wv * 64),
            16, 0, 0);
    }
}

// ---- attention (waves 0-7): wave wv owns row t0+wv; k,v,g,i via agent loads. ----
__device__ __forceinline__ void attn_row(int t0,
        const float* __restrict__ kb, const float* __restrict__ vb,
        const float* __restrict__ qs, const float* __restrict__ os,
        const float* __restrict__ g, const float* __restrict__ iexp,
        float* __restrict__ hs) {
    int tid = threadIdx.x;
    int wv = tid >> 6, lane = tid & 63;
    if (wv >= 8) return;
    int t = t0 + wv;
    float2 q2 = *(const float2*)(qs + wv * SP + 2 * lane);
    float2 o2 = *(const float2*)(os + wv * SP + 2 * lane);
    int tp = t;
    float2 k2 = load_f2_agent(kb + tp * HH + 2 * lane);
    float2 v2 = load_f2_agent(vb + tp * HH + 2 * lane);
    float ie = load_f_agent(iexp + tp), gv = load_f_agent(g + tp);
    float nx = 0.f, ny = 0.f, dsum = 0.f, decay = 1.f;
    while (true) {
        bool cont = (tp > 0) && (gv != 0.f);
        float2 k2n = {0.f, 0.f}, v2n = {0.f, 0.f};
        float ien = 0.f, gvn = 0.f;
        if (cont) {  // prefetch next step; overlaps the reduce below
            k2n = load_f2_agent(kb + (tp - 1) * HH + 2 * lane);
            v2n = load_f2_agent(vb + (tp - 1) * HH + 2 * lane);
            ien = load_f_agent(iexp + tp - 1); gvn = load_f_agent(g + tp - 1);
        }
        float p = k2.x * q2.x + k2.y * q2.y;
#pragma unroll
        for (int off = 1; off <= 32; off <<= 1) p += __shfl_xor(p, off, 64);
        float coeff = decay * ie * p;
        nx += coeff * v2.x; ny += coeff * v2.y; dsum += coeff;
        if (!cont) break;
        decay *= gv;
        tp--; k2 = k2n; v2 = v2n; ie = ien; gv = gvn;
    }
    float inv = 1.f / fmaxf(fabsf(dsum), 1.f);
    int d = 2 * lane;
    *(float2*)(hs + wv * XR + (d >> 5) * 36 + (d & 31)) =
        make_float2(o2.x * nx * inv, o2.y * ny * inv);
}

// ---- f/i scalar gates (waves 0-7): wave wv handles row wv. ----
__device__ __forceinline__ void proj_fi(int t0, const float* __restrict__ xls,
        const float* __restrict__ w_f, const float* __restrict__ b_f,
        const float* __restrict__ w_i, const float* __restrict__ b_i,
        const int* __restrict__ start, float* __restrict__ g, float* __restrict__ iexp) {
    int tid = threadIdx.x;
    int wv = tid >> 6, lane = tid & 63;
    if (wv >= 8) return;
    int d = 2 * lane;
    float2 xv = *(const float2*)(xls + wv * XR + (d >> 5) * 36 + (d & 31));
    float pf = xv.x * w_f[d] + xv.y * w_f[d + 1];
    float pi = xv.x * w_i[d] + xv.y * w_i[d + 1];
#pragma unroll
    for (int off = 1; off <= 32; off <<= 1) {
        pf += __shfl_xor(pf, off, 64);
        pi += __shfl_xor(pi, off, 64);
    }
    if (lane == 0) {
        int t = t0 + wv;
        store_f_agent(g + t, start[t] ? 0.f : 1.f / (1.f + expf(-(pf + b_f[0]))));
        store_f_agent(iexp + t, expf(pi + b_i[0]));
    }
}

// ---- 4 projections, 16 waves, no weight redundancy:
//      lane=(kc4,c16); wave w: cslot=(w&7)*16+c; mp=w>>3 picks {v,q} or {k,o}. ----
__device__ __forceinline__ void proj_block(int t0, const float* __restrict__ xls,
        const float4* __restrict__ wc,
        const float* __restrict__ b_v, const float* __restrict__ b_q,
        const float* __restrict__ b_k, const float* __restrict__ b_o,
        float* __restrict__ kb, float* __restrict__ vb,
        float* __restrict__ qs, float* __restrict__ os) {
    int tid = threadIdx.x;
    int lane = tid & 63, w = tid >> 6;
    int kc = lane >> 4, c = lane & 15;
    int cslot = (w & 7) * 16 + c;
    int mp = w >> 3;  // wave-uniform: 0 -> {v,q}, 1 -> {k,o}
    float a0[8] = {}, a1[8] = {};
#pragma unroll
    for (int j = 0; j < 8; ++j) {
        const float4* wb = wc + (kc * 8 + j) * 512 + mp * 256;
        float4 w0 = wb[cslot];
        float4 w1 = wb[128 + cslot];
#pragma unroll
        for (int rr = 0; rr < 8; ++rr) {
            float4 x4 = *(const float4*)(xls + rr * XR + kc * 36 + 4 * j);
            a0[rr] += dot4(x4, w0);
            a1[rr] += dot4(x4, w1);
        }
    }
#pragma unroll
    for (int rr = 0; rr < 8; ++rr) {
        a0[rr] += __shfl_xor(a0[rr], 16, 64); a0[rr] += __shfl_xor(a0[rr], 32, 64);
        a1[rr] += __shfl_xor(a1[rr], 16, 64); a1[rr] += __shfl_xor(a1[rr], 32, 64);
    }
    if (kc == 0) {
        if (mp == 0) {
            float bv = b_v[cslot], bq = b_q[cslot];
#pragma unroll
            for (int rr = 0; rr < 8; ++rr) {
                store_f_agent(vb + (t0 + rr) * HH + cslot, a0[rr] + bv);
                qs[rr * SP + cslot] = a1[rr] + bq;
            }
        } else {
            const float ks = 0.088388347648318447f;  // 1/sqrt(128)
            float bk = b_k[cslot], bo = b_o[cslot];
#pragma unroll
            for (int rr = 0; rr < 8; ++rr) {
                store_f_agent(kb + (t0 + rr) * HH + cslot, a0[rr] * ks + bk);
                os[rr * SP + cslot] = 1.f / (1.f + expf(-(a1[rr] + bo)));
            }
        }
    }
}

// ---- ff: 16 waves; lane=(kc8,c8); wave w: cslot=(w&7)*8+c, col=(w>>3)*64+cslot. ----
__device__ __forceinline__ void ff_block(const float* __restrict__ hsb,
        const float* __restrict__ esb, const float4* wffl,
        const float* __restrict__ b_ff, float* __restrict__ zs) {
    int tid = threadIdx.x;
    int lane = tid & 63, w = tid >> 6;
    int kc = lane >> 3, c = lane & 7;
    int col = (w >> 3) * 64 + (w & 7) * 8 + c;
    const float* xb = (kc < 4) ? hsb : esb;
    int coff = (kc & 3) * 36;
    float a0[8] = {};
#pragma unroll
    for (int j = 0; j < 8; ++j) {
        float4 w0 = wffl[(kc * 8 + j) * 128 + col];
#pragma unroll
        for (int rr = 0; rr < 8; ++rr) {
            float4 x4 = *(const float4*)(xb + rr * XR + coff + 4 * j);
            a0[rr] += dot4(x4, w0);
        }
    }
#pragma unroll
    for (int rr = 0; rr < 8; ++rr) {
        a0[rr] += __shfl_xor(a0[rr], 8, 64);
        a0[rr] += __shfl_xor(a0[rr], 16, 64);
        a0[rr] += __shfl_xor(a0[rr], 32, 64);
    }
    if (kc == 0) {
        float bb = b_ff[col];
#pragma unroll
        for (int rr = 0; rr < 8; ++rr) {
            float z = a0[rr] + bb;
            z = z > 0.f ? z : 0.01f * z;
            zs[xidx(rr, col)] = z;
        }
    }
}

// ---- 128->128 dense, 16 waves: lane=(kc8,c8); col=(w>>3)*64+(w&7)*8+c. ----
__device__ __forceinline__ void dense128(int t0, const float* __restrict__ xls,
        const float4* __restrict__ Wp, const float* __restrict__ b,
        float* __restrict__ yg, float* __restrict__ ys) {
    int tid = threadIdx.x;
    int lane = tid & 63, w = tid >> 6;
    int kc = lane >> 3, c = lane & 7;
    int col = (w >> 3) * 64 + (w & 7) * 8 + c;
    float a0[8] = {};
#pragma unroll
    for (int j = 0; j < 4; ++j) {
        float4 w0 = Wp[(kc * 4 + j) * 128 + col];
        int off = (kc >> 1) * 36 + (kc & 1) * 16 + 4 * j;
#pragma unroll
        for (int rr = 0; rr < 8; ++rr) {
            float4 x4 = *(const float4*)(xls + rr * XR + off);
            a0[rr] += dot4(x4, w0);
        }
    }
#pragma unroll
    for (int rr = 0; rr < 8; ++rr) {
        a0[rr] += __shfl_xor(a0[rr], 8, 64);
        a0[rr] += __shfl_xor(a0[rr], 16, 64);
        a0[rr] += __shfl_xor(a0[rr], 32, 64);
    }
    if (kc == 0) {
        float bb = b[col];
#pragma unroll
        for (int rr = 0; rr < 8; ++rr) {
            float y = a0[rr] + bb;
            if (ys) ys[xidx(rr, col)] = y;
            if (yg) yg[(t0 + rr) * HH + col] = y;
        }
    }
}

// ---------------- fused: P0 | barrier | P1 | barrier | P2 (1024 thr, 1 blk/CU) ------
__global__ __launch_bounds__(1024, 4) void mega_kernel(
        const float* __restrict__ emb, const int* __restrict__ start,
        const float4* __restrict__ win_p, const float* __restrict__ b_in,
        const float4* __restrict__ wcat,
        const float* __restrict__ b_v, const float* __restrict__ b_q,
        const float* __restrict__ b_k, const float* __restrict__ b_o,
        const float* __restrict__ w_f, const float* __restrict__ b_f,
        const float* __restrict__ w_i, const float* __restrict__ b_i,
        const float4* __restrict__ wff_p, const float* __restrict__ b_ff,
        const float4* __restrict__ wout_p, const float* __restrict__ b_out,
        float* __restrict__ k0b, float* __restrict__ v0b,
        float* __restrict__ k1b, float* __restrict__ v1b,
        float* __restrict__ g0, float* __restrict__ i0,
        float* __restrict__ g1, float* __restrict__ i1,
        unsigned* __restrict__ bar,
        float* __restrict__ out) {
    __shared__ float xs[ROWS * XR];
    __shared__ float es[ROWS * XR];
    __shared__ float hs[ROWS * XR];
    __shared__ float zs[ROWS * XR];
    __shared__ float qs[ROWS * SP];
    __shared__ float os[ROWS * SP];
    __shared__ float4 wsh[8192];  // 128 KB staged ff panel
    int tid = threadIdx.x;
    int t0 = blockIdx.x * ROWS;

    // ---- P0 ----
    {
        int row = tid >> 7, dd = tid & 127;
        xs[row * XR + (dd >> 5) * 36 + (dd & 31)] = emb[(t0 + row) * HH + dd];
    }
    __syncthreads();
    dense128(t0, xs, win_p, b_in, (float*)0, es);
    __syncthreads();
    proj_block(t0, es, wcat, b_v, b_q, b_k, b_o, k0b, v0b, qs, os);
    proj_fi(t0, es, w_f, b_f, w_i, b_i, start, g0, i0);
    grid_barrier(bar + 0);

    // ---- P1: stage wff0 under attn0 latency, then ff0 from LDS, proj1 ----
    stage_wsh(wff_p, wsh);
    attn_row(t0, k0b, v0b, qs, os, g0, i0, hs);
    __syncthreads();  // drains staging (vmcnt 0) + hs visible
    ff_block(hs, es, wsh, b_ff, zs);
    __syncthreads();
    proj_block(t0, zs, wcat + 16384, b_v + HH, b_q + HH, b_k + HH, b_o + HH,
               k1b, v1b, qs, os);
    proj_fi(t0, zs, w_f + HH, b_f + 1, w_i + HH, b_i + 1, start, g1, i1);
    grid_barrier(bar + 1);

    // ---- P2: stage wff1 under attn1, ff1 from LDS, final dense ----
    stage_wsh(wff_p + 8192, wsh);
    attn_row(t0, k1b, v1b, qs, os, g1, i1, hs);
    __syncthreads();
    ff_block(hs, es, wsh, b_ff + HH, zs);
    __syncthreads();
    dense128(t0, zs, wout_p, b_out, out, (float*)0);
}

extern "C" void kernel_launch(void* const* d_in, const int* in_sizes, int n_in,
                              void* d_out, int out_size, void* d_ws, size_t ws_size,
                              hipStream_t stream) {
    const float* emb   = (const float*)d_in[0];
    const int*   start = (const int*)  d_in[1];
    const float* w_in  = (const float*)d_in[2];
    const float* b_in  = (const float*)d_in[3];
    const float* w_out = (const float*)d_in[4];
    const float* b_out = (const float*)d_in[5];
    const float* w_f   = (const float*)d_in[6];
    const float* b_f   = (const float*)d_in[7];
    const float* w_i   = (const float*)d_in[8];
    const float* b_i   = (const float*)d_in[9];
    const float* w_v   = (const float*)d_in[10];
    const float* b_v   = (const float*)d_in[11];
    const float* w_q   = (const float*)d_in[12];
    const float* b_q   = (const float*)d_in[13];
    const float* w_k   = (const float*)d_in[14];
    const float* b_k   = (const float*)d_in[15];
    const float* w_o   = (const float*)d_in[16];
    const float* b_o   = (const float*)d_in[17];
    const float* w_ff  = (const float*)d_in[18];
    const float* b_ff  = (const float*)d_in[19];
    float* out = (float*)d_out;

    unsigned* bar = (unsigned*)d_ws;            // 16 counters, zeroed by prep
    float* ws = (float*)d_ws + 64;
    float* k0b = ws; ws += TT * HH;
    float* v0b = ws; ws += TT * HH;
    float* k1b = ws; ws += TT * HH;
    float* v1b = ws; ws += TT * HH;
    float* g0  = ws; ws += TT;
    float* i0  = ws; ws += TT;
    float* g1  = ws; ws += TT;
    float* i1  = ws; ws += TT;
    float4* win_p  = (float4*)ws; ws += 16384;   // 4096 float4
    float4* wout_p = (float4*)ws; ws += 16384;   // 4096 float4
    float4* wcat   = (float4*)ws; ws += 131072;  // 32768 float4 (2 layers)
    float4* wff_p  = (float4*)ws; ws += 65536;   // 16384 float4 (2 layers)

    prep_kernel<<<dim3(224), dim3(256), 0, stream>>>(
        w_in, w_out, w_v, w_q, w_k, w_o, w_ff, win_p, wout_p, wcat, wff_p, bar);
    mega_kernel<<<dim3(NBLK), dim3(1024), 0, stream>>>(
        emb, start, win_p, b_in, wcat,
        b_v, b_q, b_k, b_o, w_f, b_f, w_i, b_i,
        wff_p, b_ff, wout_p, b_out,
        k0b, v0b, k1b, v1b, g0, i0, g1, i1,
        bar, out);
}

// Round 10
// 138.041 us; speedup vs baseline: 1.0534x; 1.0263x over previous
//
#include <hip/hip_runtime.h>
#include <math.h>

#define TT 2048
#define HH 128
#define ROWS 8
#define SP 132   // row-major LDS stride (qs, os, zp)
#define XR 144   // chunk-padded LDS row stride: 4 chunks x 36
#define NBLK (TT / ROWS)

__device__ __forceinline__ float dot4(float4 a, float4 b) {
    return a.x * b.x + a.y * b.y + a.z * b.z + a.w * b.w;
}

// chunk-padded x index: element k of row r lives at r*XR + (k>>5)*36 + (k&31)
__device__ __forceinline__ int xidx(int r, int k) {
    return r * XR + ((k >> 5) * 36) + (k & 31);
}

// ---- agent-scope (cross-XCD coherent, L1/L2-bypassing) accessors for kv/gi ----
__device__ __forceinline__ float2 load_f2_agent(const float* p) {
    unsigned long long u = __hip_atomic_load((const unsigned long long*)p,
                                             __ATOMIC_RELAXED, __HIP_MEMORY_SCOPE_AGENT);
    float2 r;
    r.x = __uint_as_float((unsigned)(u & 0xffffffffull));
    r.y = __uint_as_float((unsigned)(u >> 32));
    return r;
}
__device__ __forceinline__ float load_f_agent(const float* p) {
    return __hip_atomic_load(p, __ATOMIC_RELAXED, __HIP_MEMORY_SCOPE_AGENT);
}
__device__ __forceinline__ void store_f_agent(float* p, float v) {
    __hip_atomic_store(p, v, __ATOMIC_RELAXED, __HIP_MEMORY_SCOPE_AGENT);
}

// ---------------- prep: pack weights + zero barrier ctrs + episode starts ----
__global__ __launch_bounds__(256) void prep_kernel(
        const float* __restrict__ w_in, const float* __restrict__ w_out,
        const float* __restrict__ w_v, const float* __restrict__ w_q,
        const float* __restrict__ w_k, const float* __restrict__ w_o,
        const float* __restrict__ w_ff, const int* __restrict__ start,
        float4* __restrict__ win_p, float4* __restrict__ wout_p,
        float4* __restrict__ wcat, float4* __restrict__ wff_p,
        int* __restrict__ stb, unsigned* __restrict__ bar) {
    if (blockIdx.x >= 224) {
        // episode-start scan: st[t] = largest s<=t with start[s]==1, else 0
        __shared__ int sl[256];
        int base = (blockIdx.x - 224) * 256;
        int t = base + threadIdx.x;
        sl[threadIdx.x] = start[t];
        __syncthreads();
        int s = t;
        while (s > base && sl[s - base] == 0) --s;
        if (s == base && sl[0] == 0) {
            while (s > 0 && start[s] == 0) --s;  // rare cross-block fallback
        }
        stb[t] = s;
        return;
    }
    int i = blockIdx.x * 256 + threadIdx.x;
    if (blockIdx.x == 0 && threadIdx.x < 16) bar[threadIdx.x] = 0u;
    if (i < 4096) {
        int cg = i >> 7, col = i & 127;
        win_p[i] = ((const float4*)w_in)[col * 32 + cg];
    } else if (i < 8192) {
        int j = i - 4096, cg = j >> 7, col = j & 127;
        wout_p[j] = ((const float4*)w_out)[col * 32 + cg];
    } else if (i < 40960) {
        int j = i - 8192;
        int l = j >> 14, r = j & 16383, cg = r >> 9, col = r & 511;
        int sel = col >> 7, cm = col & 127;
        const float* s = (sel == 0 ? w_v : sel == 1 ? w_q : sel == 2 ? w_k : w_o) + l * HH * HH;
        wcat[j] = ((const float4*)s)[cm * 32 + cg];
    } else {
        int j = i - 40960;
        int l = j >> 13, r = j & 8191, cg = r >> 7, col = r & 127;
        const float* s = w_ff + l * HH * 256;
        wff_p[j] = ((const float4*)s)[col * 64 + cg];
    }
}

// ---- device-wide barrier WITHOUT agent fences (no L2 wb/inv — weights stay warm). ----
__device__ __forceinline__ void grid_barrier(unsigned* __restrict__ ctr) {
    __syncthreads();  // compiler emits s_waitcnt vmcnt(0) lgkmcnt(0) before s_barrier
    if (threadIdx.x == 0) {
        atomicAdd(ctr, 1u);  // device-scope atomic, coherent at L3
        while (__hip_atomic_load(ctr, __ATOMIC_RELAXED, __HIP_MEMORY_SCOPE_AGENT)
               < (unsigned)NBLK) {
            __builtin_amdgcn_s_sleep(8);
        }
    }
    __syncthreads();
}

// ---- attention (waves 0-7): batched 4-step loads using precomputed episode start. ----
__device__ __forceinline__ void attn_row(int t0,
        const float* __restrict__ kb, const float* __restrict__ vb,
        const float* __restrict__ qs, const float* __restrict__ os,
        const float* __restrict__ g, const float* __restrict__ iexp,
        const int* __restrict__ stb, float* __restrict__ hs) {
    int tid = threadIdx.x;
    int wv = tid >> 6, lane = tid & 63;
    int t = t0 + wv;
    int st = stb[t];
    float2 q2 = *(const float2*)(qs + wv * SP + 2 * lane);
    float2 o2 = *(const float2*)(os + wv * SP + 2 * lane);
    float nx = 0.f, ny = 0.f, dsum = 0.f, decay = 1.f;
    int tp = t;
    while (tp >= st) {
        int nb = tp - st + 1; if (nb > 4) nb = 4;
        float2 kk[4], vv[4];
        float ie[4], gv[4];
#pragma unroll
        for (int b = 0; b < 4; ++b) {
            if (b < nb) {  // 4 independent step-loads in flight (one L3 latency)
                kk[b] = load_f2_agent(kb + (tp - b) * HH + 2 * lane);
                vv[b] = load_f2_agent(vb + (tp - b) * HH + 2 * lane);
                ie[b] = load_f_agent(iexp + (tp - b));
                gv[b] = load_f_agent(g + (tp - b));
            }
        }
#pragma unroll
        for (int b = 0; b < 4; ++b) {
            if (b < nb) {
                float p = kk[b].x * q2.x + kk[b].y * q2.y;
#pragma unroll
                for (int off = 1; off <= 32; off <<= 1) p += __shfl_xor(p, off, 64);
                float coeff = decay * ie[b] * p;
                nx += coeff * vv[b].x; ny += coeff * vv[b].y; dsum += coeff;
                if (tp - b > st) decay *= gv[b];  // g==0 mid-episode -> decay 0, same math
            }
        }
        tp -= nb;
    }
    float inv = 1.f / fmaxf(fabsf(dsum), 1.f);
    int d = 2 * lane;
    *(float2*)(hs + wv * XR + (d >> 5) * 36 + (d & 31)) =
        make_float2(o2.x * nx * inv, o2.y * ny * inv);
}

// ---- f/i scalar gates (waves 0-7): wave wv handles row wv. ----
__device__ __forceinline__ void proj_fi(int t0, const float* __restrict__ xls,
        const float* __restrict__ w_f, const float* __restrict__ b_f,
        const float* __restrict__ w_i, const float* __restrict__ b_i,
        const int* __restrict__ start, float* __restrict__ g, float* __restrict__ iexp) {
    int tid = threadIdx.x;
    int wv = tid >> 6, lane = tid & 63;
    if (wv >= 8) return;
    int d = 2 * lane;
    float2 xv = *(const float2*)(xls + wv * XR + (d >> 5) * 36 + (d & 31));
    float pf = xv.x * w_f[d] + xv.y * w_f[d + 1];
    float pi = xv.x * w_i[d] + xv.y * w_i[d + 1];
#pragma unroll
    for (int off = 1; off <= 32; off <<= 1) {
        pf += __shfl_xor(pf, off, 64);
        pi += __shfl_xor(pi, off, 64);
    }
    if (lane == 0) {
        int t = t0 + wv;
        store_f_agent(g + t, start[t] ? 0.f : 1.f / (1.f + expf(-(pf + b_f[0]))));
        store_f_agent(iexp + t, expf(pi + b_i[0]));
    }
}

// ---- 4 projections, 16 waves, no weight redundancy (r9 layout). ----
__device__ __forceinline__ void proj_block(int t0, const float* __restrict__ xls,
        const float4* __restrict__ wc,
        const float* __restrict__ b_v, const float* __restrict__ b_q,
        const float* __restrict__ b_k, const float* __restrict__ b_o,
        float* __restrict__ kb, float* __restrict__ vb,
        float* __restrict__ qs, float* __restrict__ os) {
    int tid = threadIdx.x;
    int lane = tid & 63, w = tid >> 6;
    int kc = lane >> 4, c = lane & 15;
    int cslot = (w & 7) * 16 + c;
    int mp = w >> 3;  // wave-uniform: 0 -> {v,q}, 1 -> {k,o}
    float a0[8] = {}, a1[8] = {};
#pragma unroll
    for (int j = 0; j < 8; ++j) {
        const float4* wb = wc + (kc * 8 + j) * 512 + mp * 256;
        float4 w0 = wb[cslot];
        float4 w1 = wb[128 + cslot];
#pragma unroll
        for (int rr = 0; rr < 8; ++rr) {
            float4 x4 = *(const float4*)(xls + rr * XR + kc * 36 + 4 * j);
            a0[rr] += dot4(x4, w0);
            a1[rr] += dot4(x4, w1);
        }
    }
#pragma unroll
    for (int rr = 0; rr < 8; ++rr) {
        a0[rr] += __shfl_xor(a0[rr], 16, 64); a0[rr] += __shfl_xor(a0[rr], 32, 64);
        a1[rr] += __shfl_xor(a1[rr], 16, 64); a1[rr] += __shfl_xor(a1[rr], 32, 64);
    }
    if (kc == 0) {
        if (mp == 0) {
            float bv = b_v[cslot], bq = b_q[cslot];
#pragma unroll
            for (int rr = 0; rr < 8; ++rr) {
                store_f_agent(vb + (t0 + rr) * HH + cslot, a0[rr] + bv);
                qs[rr * SP + cslot] = a1[rr] + bq;
            }
        } else {
            const float ks = 0.088388347648318447f;  // 1/sqrt(128)
            float bk = b_k[cslot], bo = b_o[cslot];
#pragma unroll
            for (int rr = 0; rr < 8; ++rr) {
                store_f_agent(kb + (t0 + rr) * HH + cslot, a0[rr] * ks + bk);
                os[rr * SP + cslot] = 1.f / (1.f + expf(-(a1[rr] + bo)));
            }
        }
    }
}

// ---- ff e-half (waves 8-15, runs UNDER attention): partial z from es only.
//      Weights read from GLOBAL (e-rows 32..63 of the packed panel). ----
__device__ __forceinline__ void ffe_block(const float* __restrict__ esb,
        const float4* __restrict__ wffg, float* __restrict__ zp) {
    int tid = threadIdx.x;
    int lane = tid & 63, w = tid >> 6;
    int kc = lane >> 4, c = lane & 15;
    int cslot = (w - 8) * 16 + c;  // 128 cols across waves 8-15
    float acc[8] = {};
#pragma unroll
    for (int j = 0; j < 8; ++j) {
        float4 w0 = wffg[(32 + kc * 8 + j) * 128 + cslot];
#pragma unroll
        for (int rr = 0; rr < 8; ++rr) {
            float4 x4 = *(const float4*)(esb + rr * XR + kc * 36 + 4 * j);
            acc[rr] += dot4(x4, w0);
        }
    }
#pragma unroll
    for (int rr = 0; rr < 8; ++rr) {
        acc[rr] += __shfl_xor(acc[rr], 16, 64);
        acc[rr] += __shfl_xor(acc[rr], 32, 64);
    }
    if (kc == 0) {
#pragma unroll
        for (int rr = 0; rr < 8; ++rr) zp[rr * SP + cslot] = acc[rr];
    }
}

// ---- ff h-half (16 waves, post-attention): z = lrelu(h-GEMV + zp + b). Weights LDS. ----
__device__ __forceinline__ void ffh_block(const float* __restrict__ hsb,
        const float4* wshl, const float* __restrict__ zp,
        const float* __restrict__ b_ff, float* __restrict__ zs) {
    int tid = threadIdx.x;
    int lane = tid & 63, w = tid >> 6;
    int kc = lane >> 4, c = lane & 15;
    int rg = w >> 3;                 // rows rg*4..rg*4+3
    int cslot = (w & 7) * 16 + c;
    float acc[4] = {};
#pragma unroll
    for (int j = 0; j < 8; ++j) {
        float4 w0 = wshl[(kc * 8 + j) * 128 + cslot];
#pragma unroll
        for (int rr = 0; rr < 4; ++rr) {
            float4 x4 = *(const float4*)(hsb + (rg * 4 + rr) * XR + kc * 36 + 4 * j);
            acc[rr] += dot4(x4, w0);
        }
    }
#pragma unroll
    for (int rr = 0; rr < 4; ++rr) {
        acc[rr] += __shfl_xor(acc[rr], 16, 64);
        acc[rr] += __shfl_xor(acc[rr], 32, 64);
    }
    if (kc == 0) {
        float bb = b_ff[cslot];
#pragma unroll
        for (int rr = 0; rr < 4; ++rr) {
            int r = rg * 4 + rr;
            float z = acc[rr] + zp[r * SP + cslot] + bb;
            z = z > 0.f ? z : 0.01f * z;
            zs[xidx(r, cslot)] = z;
        }
    }
}

// ---- 128->128 dense, 16 waves (r9 layout). ----
__device__ __forceinline__ void dense128(int t0, const float* __restrict__ xls,
        const float4* __restrict__ Wp, const float* __restrict__ b,
        float* __restrict__ yg, float* __restrict__ ys) {
    int tid = threadIdx.x;
    int lane = tid & 63, w = tid >> 6;
    int kc = lane >> 3, c = lane & 7;
    int col = (w >> 3) * 64 + (w & 7) * 8 + c;
    float a0[8] = {};
#pragma unroll
    for (int j = 0; j < 4; ++j) {
        float4 w0 = Wp[(kc * 4 + j) * 128 + col];
        int off = (kc >> 1) * 36 + (kc & 1) * 16 + 4 * j;
#pragma unroll
        for (int rr = 0; rr < 8; ++rr) {
            float4 x4 = *(const float4*)(xls + rr * XR + off);
            a0[rr] += dot4(x4, w0);
        }
    }
#pragma unroll
    for (int rr = 0; rr < 8; ++rr) {
        a0[rr] += __shfl_xor(a0[rr], 8, 64);
        a0[rr] += __shfl_xor(a0[rr], 16, 64);
        a0[rr] += __shfl_xor(a0[rr], 32, 64);
    }
    if (kc == 0) {
        float bb = b[col];
#pragma unroll
        for (int rr = 0; rr < 8; ++rr) {
            float y = a0[rr] + bb;
            if (ys) ys[xidx(rr, col)] = y;
            if (yg) yg[(t0 + rr) * HH + col] = y;
        }
    }
}

// ---- stage h-half ff panel (64 KB = 4096 float4) by waves 8-15 only. ----
__device__ __forceinline__ void stage_wsh_h(const float4* __restrict__ src, float4* lds) {
    int tid2 = threadIdx.x - 512;       // 0..511 within waves 8-15
    int wv2 = tid2 >> 6;
#pragma unroll
    for (int it = 0; it < 8; ++it) {
        __builtin_amdgcn_global_load_lds(
            (const __attribute__((address_space(1))) unsigned int*)(src + it * 512 + tid2),
            (__attribute__((address_space(3))) unsigned int*)(lds + it * 512 + wv2 * 64),
            16, 0, 0);
    }
}

// ---------------- fused: P0 | barrier | P1 | barrier | P2 (1024 thr, 1 blk/CU) ------
__global__ __launch_bounds__(1024, 4) void mega_kernel(
        const float* __restrict__ emb, const int* __restrict__ start,
        const float4* __restrict__ win_p, const float* __restrict__ b_in,
        const float4* __restrict__ wcat,
        const float* __restrict__ b_v, const float* __restrict__ b_q,
        const float* __restrict__ b_k, const float* __restrict__ b_o,
        const float* __restrict__ w_f, const float* __restrict__ b_f,
        const float* __restrict__ w_i, const float* __restrict__ b_i,
        const float4* __restrict__ wff_p, const float* __restrict__ b_ff,
        const float4* __restrict__ wout_p, const float* __restrict__ b_out,
        float* __restrict__ k0b, float* __restrict__ v0b,
        float* __restrict__ k1b, float* __restrict__ v1b,
        float* __restrict__ g0, float* __restrict__ i0,
        float* __restrict__ g1, float* __restrict__ i1,
        const int* __restrict__ stb, unsigned* __restrict__ bar,
        float* __restrict__ out) {
    __shared__ float xs[ROWS * XR];
    __shared__ float es[ROWS * XR];
    __shared__ float hs[ROWS * XR];
    __shared__ float zs[ROWS * XR];
    __shared__ float qs[ROWS * SP];
    __shared__ float os[ROWS * SP];
    __shared__ float zp[ROWS * SP];
    __shared__ float4 wsh[4096];  // 64 KB staged ff h-half panel
    int tid = threadIdx.x;
    int t0 = blockIdx.x * ROWS;
    int wv = tid >> 6;

    // ---- P0 ----
    {
        int row = tid >> 7, dd = tid & 127;
        xs[row * XR + (dd >> 5) * 36 + (dd & 31)] = emb[(t0 + row) * HH + dd];
    }
    __syncthreads();
    dense128(t0, xs, win_p, b_in, (float*)0, es);
    __syncthreads();
    proj_block(t0, es, wcat, b_v, b_q, b_k, b_o, k0b, v0b, qs, os);
    proj_fi(t0, es, w_f, b_f, w_i, b_i, start, g0, i0);
    grid_barrier(bar + 0);

    // ---- P1: waves 0-7 attn0 | waves 8-15 stage h-panel + e-half ff0 ----
    if (wv < 8) {
        attn_row(t0, k0b, v0b, qs, os, g0, i0, stb, hs);
    } else {
        stage_wsh_h(wff_p, wsh);
        ffe_block(es, wff_p, zp);
    }
    __syncthreads();  // drains staging (vmcnt 0) + hs/zp visible
    ffh_block(hs, wsh, zp, b_ff, zs);
    __syncthreads();
    proj_block(t0, zs, wcat + 16384, b_v + HH, b_q + HH, b_k + HH, b_o + HH,
               k1b, v1b, qs, os);
    proj_fi(t0, zs, w_f + HH, b_f + 1, w_i + HH, b_i + 1, start, g1, i1);
    grid_barrier(bar + 1);

    // ---- P2: waves 0-7 attn1 | waves 8-15 stage + e-half ff1; then final dense ----
    if (wv < 8) {
        attn_row(t0, k1b, v1b, qs, os, g1, i1, stb, hs);
    } else {
        stage_wsh_h(wff_p + 8192, wsh);
        ffe_block(es, wff_p + 8192, zp);
    }
    __syncthreads();
    ffh_block(hs, wsh, zp, b_ff + HH, zs);
    __syncthreads();
    dense128(t0, zs, wout_p, b_out, out, (float*)0);
}

extern "C" void kernel_launch(void* const* d_in, const int* in_sizes, int n_in,
                              void* d_out, int out_size, void* d_ws, size_t ws_size,
                              hipStream_t stream) {
    const float* emb   = (const float*)d_in[0];
    const int*   start = (const int*)  d_in[1];
    const float* w_in  = (const float*)d_in[2];
    const float* b_in  = (const float*)d_in[3];
    const float* w_out = (const float*)d_in[4];
    const float* b_out = (const float*)d_in[5];
    const float* w_f   = (const float*)d_in[6];
    const float* b_f   = (const float*)d_in[7];
    const float* w_i   = (const float*)d_in[8];
    const float* b_i   = (const float*)d_in[9];
    const float* w_v   = (const float*)d_in[10];
    const float* b_v   = (const float*)d_in[11];
    const float* w_q   = (const float*)d_in[12];
    const float* b_q   = (const float*)d_in[13];
    const float* w_k   = (const float*)d_in[14];
    const float* b_k   = (const float*)d_in[15];
    const float* w_o   = (const float*)d_in[16];
    const float* b_o   = (const float*)d_in[17];
    const float* w_ff  = (const float*)d_in[18];
    const float* b_ff  = (const float*)d_in[19];
    float* out = (float*)d_out;

    unsigned* bar = (unsigned*)d_ws;            // 16 counters, zeroed by prep
    float* ws = (float*)d_ws + 64;
    float* k0b = ws; ws += TT * HH;
    float* v0b = ws; ws += TT * HH;
    float* k1b = ws; ws += TT * HH;
    float* v1b = ws; ws += TT * HH;
    float* g0  = ws; ws += TT;
    float* i0  = ws; ws += TT;
    float* g1  = ws; ws += TT;
    float* i1  = ws; ws += TT;
    int* stb   = (int*)ws; ws += TT;             // episode starts
    float4* win_p  = (float4*)ws; ws += 16384;   // 4096 float4
    float4* wout_p = (float4*)ws; ws += 16384;   // 4096 float4
    float4* wcat   = (float4*)ws; ws += 131072;  // 32768 float4 (2 layers)
    float4* wff_p  = (float4*)ws; ws += 65536;   // 16384 float4 (2 layers)

    prep_kernel<<<dim3(232), dim3(256), 0, stream>>>(
        w_in, w_out, w_v, w_q, w_k, w_o, w_ff, start,
        win_p, wout_p, wcat, wff_p, stb, bar);
    mega_kernel<<<dim3(NBLK), dim3(1024), 0, stream>>>(
        emb, start, win_p, b_in, wcat,
        b_v, b_q, b_k, b_o, w_f, b_f, w_i, b_i,
        wff_p, b_ff, wout_p, b_out,
        k0b, v0b, k1b, v1b, g0, i0, g1, i1,
        stb, bar, out);
}

// Round 11
// 125.172 us; speedup vs baseline: 1.1617x; 1.1028x over previous
//
#include <hip/hip_runtime.h>
#include <math.h>

#define TT 2048
#define HH 128
#define ROWS 8
#define SP 132   // row-major LDS stride (qs, os, zp, kl, vl)
#define XR 144   // chunk-padded LDS row stride: 4 chunks x 36
#define NBLK (TT / ROWS)

__device__ __forceinline__ float dot4(float4 a, float4 b) {
    return a.x * b.x + a.y * b.y + a.z * b.z + a.w * b.w;
}

// chunk-padded x index: element k of row r lives at r*XR + (k>>5)*36 + (k&31)
__device__ __forceinline__ int xidx(int r, int k) {
    return r * XR + ((k >> 5) * 36) + (k & 31);
}

// ---- agent-scope (cross-XCD coherent, L1/L2-bypassing) accessors ----
__device__ __forceinline__ float2 load_f2_agent(const float* p) {
    unsigned long long u = __hip_atomic_load((const unsigned long long*)p,
                                             __ATOMIC_RELAXED, __HIP_MEMORY_SCOPE_AGENT);
    float2 r;
    r.x = __uint_as_float((unsigned)(u & 0xffffffffull));
    r.y = __uint_as_float((unsigned)(u >> 32));
    return r;
}
__device__ __forceinline__ float load_f_agent(const float* p) {
    return __hip_atomic_load(p, __ATOMIC_RELAXED, __HIP_MEMORY_SCOPE_AGENT);
}
__device__ __forceinline__ void store_f_agent(float* p, float v) {
    __hip_atomic_store(p, v, __ATOMIC_RELAXED, __HIP_MEMORY_SCOPE_AGENT);
}
__device__ __forceinline__ unsigned load_u_agent(const unsigned* p) {
    return __hip_atomic_load(p, __ATOMIC_RELAXED, __HIP_MEMORY_SCOPE_AGENT);
}

// ---------------- prep: pack weights + zero flags + episode starts ----
__global__ __launch_bounds__(256) void prep_kernel(
        const float* __restrict__ w_in, const float* __restrict__ w_out,
        const float* __restrict__ w_v, const float* __restrict__ w_q,
        const float* __restrict__ w_k, const float* __restrict__ w_o,
        const float* __restrict__ w_ff, const int* __restrict__ start,
        float4* __restrict__ win_p, float4* __restrict__ wout_p,
        float4* __restrict__ wcat, float4* __restrict__ wff_p,
        int* __restrict__ stb, unsigned* __restrict__ flags) {
    if (blockIdx.x >= 224) {
        // episode-start scan: st[t] = largest s<=t with start[s]==1, else 0
        __shared__ int sl[256];
        int base = (blockIdx.x - 224) * 256;
        int t = base + threadIdx.x;
        sl[threadIdx.x] = start[t];
        __syncthreads();
        int s = t;
        while (s > base && sl[s - base] == 0) --s;
        if (s == base && sl[0] == 0) {
            while (s > 0 && start[s] == 0) --s;  // rare cross-block fallback
        }
        stb[t] = s;
        return;
    }
    if (blockIdx.x == 0) flags[threadIdx.x] = 0u;  // 256 per-block phase flags
    int i = blockIdx.x * 256 + threadIdx.x;
    if (i < 4096) {
        int cg = i >> 7, col = i & 127;
        win_p[i] = ((const float4*)w_in)[col * 32 + cg];
    } else if (i < 8192) {
        int j = i - 4096, cg = j >> 7, col = j & 127;
        wout_p[j] = ((const float4*)w_out)[col * 32 + cg];
    } else if (i < 40960) {
        int j = i - 8192;
        int l = j >> 14, r = j & 16383, cg = r >> 9, col = r & 511;
        int sel = col >> 7, cm = col & 127;
        const float* s = (sel == 0 ? w_v : sel == 1 ? w_q : sel == 2 ? w_k : w_o) + l * HH * HH;
        wcat[j] = ((const float4*)s)[cm * 32 + cg];
    } else {
        int j = i - 40960;
        int l = j >> 13, r = j & 8191, cg = r >> 7, col = r & 127;
        const float* s = w_ff + l * HH * 256;
        wff_p[j] = ((const float4*)s)[col * 64 + cg];
    }
}

// ---- attention (waves 0-7): in-block steps from LDS; remote prefix via flags +
//      batched agent loads. No global barrier anywhere. ----
__device__ __forceinline__ void attn_row(int t0, int bid, unsigned phase,
        const unsigned* __restrict__ flags,
        const float* __restrict__ kb, const float* __restrict__ vb,
        const float* __restrict__ kl, const float* __restrict__ vl,
        const float* __restrict__ qs, const float* __restrict__ os,
        const float* __restrict__ g, const float* __restrict__ iexp,
        const float* __restrict__ gl, const float* __restrict__ il,
        const int* __restrict__ stb, float* __restrict__ hs) {
    int tid = threadIdx.x;
    int wv = tid >> 6, lane = tid & 63;
    int t = t0 + wv;
    int st = stb[t];
    float2 q2 = *(const float2*)(qs + wv * SP + 2 * lane);
    float2 o2 = *(const float2*)(os + wv * SP + 2 * lane);
    float nx = 0.f, ny = 0.f, dsum = 0.f, decay = 1.f;
    // ---- in-block part: tp in [max(st,t0), t], kv/gi from LDS ----
    int lo = st > t0 ? st : t0;
    for (int tp = t; tp >= lo; --tp) {
        int r = tp - t0;
        float2 k2 = *(const float2*)(kl + r * SP + 2 * lane);
        float2 v2 = *(const float2*)(vl + r * SP + 2 * lane);
        float p = k2.x * q2.x + k2.y * q2.y;
#pragma unroll
        for (int off = 1; off <= 32; off <<= 1) p += __shfl_xor(p, off, 64);
        float coeff = decay * il[r] * p;
        nx += coeff * v2.x; ny += coeff * v2.y; dsum += coeff;
        if (tp > st) decay *= gl[r];
    }
    // ---- remote prefix: rows [st, t0) produced by earlier blocks ----
    if (st < t0) {
        for (int j = st >> 3; j < bid; ++j) {   // ROWS == 8
            while (load_u_agent(flags + j) < phase) __builtin_amdgcn_s_sleep(1);
        }
        int tp = t0 - 1;
        while (tp >= st) {
            int nb = tp - st + 1; if (nb > 4) nb = 4;
            float2 kk[4], vv[4];
            float ie[4], gv[4];
#pragma unroll
            for (int b = 0; b < 4; ++b) {
                if (b < nb) {  // independent step-loads in flight (one L3 latency)
                    kk[b] = load_f2_agent(kb + (tp - b) * HH + 2 * lane);
                    vv[b] = load_f2_agent(vb + (tp - b) * HH + 2 * lane);
                    ie[b] = load_f_agent(iexp + (tp - b));
                    gv[b] = load_f_agent(g + (tp - b));
                }
            }
#pragma unroll
            for (int b = 0; b < 4; ++b) {
                if (b < nb) {
                    float p = kk[b].x * q2.x + kk[b].y * q2.y;
#pragma unroll
                    for (int off = 1; off <= 32; off <<= 1) p += __shfl_xor(p, off, 64);
                    float coeff = decay * ie[b] * p;
                    nx += coeff * vv[b].x; ny += coeff * vv[b].y; dsum += coeff;
                    if (tp - b > st) decay *= gv[b];
                }
            }
            tp -= nb;
        }
    }
    float inv = 1.f / fmaxf(fabsf(dsum), 1.f);
    int d = 2 * lane;
    *(float2*)(hs + wv * XR + (d >> 5) * 36 + (d & 31)) =
        make_float2(o2.x * nx * inv, o2.y * ny * inv);
}

// ---- f/i scalar gates (waves 0-7): writes global (remote readers) + LDS (own). ----
__device__ __forceinline__ void proj_fi(int t0, const float* __restrict__ xls,
        const float* __restrict__ w_f, const float* __restrict__ b_f,
        const float* __restrict__ w_i, const float* __restrict__ b_i,
        const int* __restrict__ start, float* __restrict__ g, float* __restrict__ iexp,
        float* __restrict__ gl, float* __restrict__ il) {
    int tid = threadIdx.x;
    int wv = tid >> 6, lane = tid & 63;
    if (wv >= 8) return;
    int d = 2 * lane;
    float2 xv = *(const float2*)(xls + wv * XR + (d >> 5) * 36 + (d & 31));
    float pf = xv.x * w_f[d] + xv.y * w_f[d + 1];
    float pi = xv.x * w_i[d] + xv.y * w_i[d + 1];
#pragma unroll
    for (int off = 1; off <= 32; off <<= 1) {
        pf += __shfl_xor(pf, off, 64);
        pi += __shfl_xor(pi, off, 64);
    }
    if (lane == 0) {
        int t = t0 + wv;
        float gvv = start[t] ? 0.f : 1.f / (1.f + expf(-(pf + b_f[0])));
        float ivv = expf(pi + b_i[0]);
        store_f_agent(g + t, gvv);
        store_f_agent(iexp + t, ivv);
        gl[wv] = gvv;
        il[wv] = ivv;
    }
}

// ---- 4 projections, 16 waves, no weight redundancy; kv also mirrored to LDS. ----
__device__ __forceinline__ void proj_block(int t0, const float* __restrict__ xls,
        const float4* __restrict__ wc,
        const float* __restrict__ b_v, const float* __restrict__ b_q,
        const float* __restrict__ b_k, const float* __restrict__ b_o,
        float* __restrict__ kb, float* __restrict__ vb,
        float* __restrict__ kl, float* __restrict__ vl,
        float* __restrict__ qs, float* __restrict__ os) {
    int tid = threadIdx.x;
    int lane = tid & 63, w = tid >> 6;
    int kc = lane >> 4, c = lane & 15;
    int cslot = (w & 7) * 16 + c;
    int mp = w >> 3;  // wave-uniform: 0 -> {v,q}, 1 -> {k,o}
    float a0[8] = {}, a1[8] = {};
#pragma unroll
    for (int j = 0; j < 8; ++j) {
        const float4* wb = wc + (kc * 8 + j) * 512 + mp * 256;
        float4 w0 = wb[cslot];
        float4 w1 = wb[128 + cslot];
#pragma unroll
        for (int rr = 0; rr < 8; ++rr) {
            float4 x4 = *(const float4*)(xls + rr * XR + kc * 36 + 4 * j);
            a0[rr] += dot4(x4, w0);
            a1[rr] += dot4(x4, w1);
        }
    }
#pragma unroll
    for (int rr = 0; rr < 8; ++rr) {
        a0[rr] += __shfl_xor(a0[rr], 16, 64); a0[rr] += __shfl_xor(a0[rr], 32, 64);
        a1[rr] += __shfl_xor(a1[rr], 16, 64); a1[rr] += __shfl_xor(a1[rr], 32, 64);
    }
    if (kc == 0) {
        if (mp == 0) {
            float bv = b_v[cslot], bq = b_q[cslot];
#pragma unroll
            for (int rr = 0; rr < 8; ++rr) {
                float vv = a0[rr] + bv;
                store_f_agent(vb + (t0 + rr) * HH + cslot, vv);
                vl[rr * SP + cslot] = vv;
                qs[rr * SP + cslot] = a1[rr] + bq;
            }
        } else {
            const float ks = 0.088388347648318447f;  // 1/sqrt(128)
            float bk = b_k[cslot], bo = b_o[cslot];
#pragma unroll
            for (int rr = 0; rr < 8; ++rr) {
                float kk = a0[rr] * ks + bk;
                store_f_agent(kb + (t0 + rr) * HH + cslot, kk);
                kl[rr * SP + cslot] = kk;
                os[rr * SP + cslot] = 1.f / (1.f + expf(-(a1[rr] + bo)));
            }
        }
    }
}

// ---- ff e-half (waves 8-15, runs UNDER attention): partial z from es only. ----
__device__ __forceinline__ void ffe_block(const float* __restrict__ esb,
        const float4* __restrict__ wffg, float* __restrict__ zp) {
    int tid = threadIdx.x;
    int lane = tid & 63, w = tid >> 6;
    int kc = lane >> 4, c = lane & 15;
    int cslot = (w - 8) * 16 + c;  // 128 cols across waves 8-15
    float acc[8] = {};
#pragma unroll
    for (int j = 0; j < 8; ++j) {
        float4 w0 = wffg[(32 + kc * 8 + j) * 128 + cslot];
#pragma unroll
        for (int rr = 0; rr < 8; ++rr) {
            float4 x4 = *(const float4*)(esb + rr * XR + kc * 36 + 4 * j);
            acc[rr] += dot4(x4, w0);
        }
    }
#pragma unroll
    for (int rr = 0; rr < 8; ++rr) {
        acc[rr] += __shfl_xor(acc[rr], 16, 64);
        acc[rr] += __shfl_xor(acc[rr], 32, 64);
    }
    if (kc == 0) {
#pragma unroll
        for (int rr = 0; rr < 8; ++rr) zp[rr * SP + cslot] = acc[rr];
    }
}

// ---- ff h-half (16 waves, post-attention): z = lrelu(h-GEMV + zp + b). ----
__device__ __forceinline__ void ffh_block(const float* __restrict__ hsb,
        const float4* wshl, const float* __restrict__ zp,
        const float* __restrict__ b_ff, float* __restrict__ zs) {
    int tid = threadIdx.x;
    int lane = tid & 63, w = tid >> 6;
    int kc = lane >> 4, c = lane & 15;
    int rg = w >> 3;                 // rows rg*4..rg*4+3
    int cslot = (w & 7) * 16 + c;
    float acc[4] = {};
#pragma unroll
    for (int j = 0; j < 8; ++j) {
        float4 w0 = wshl[(kc * 8 + j) * 128 + cslot];
#pragma unroll
        for (int rr = 0; rr < 4; ++rr) {
            float4 x4 = *(const float4*)(hsb + (rg * 4 + rr) * XR + kc * 36 + 4 * j);
            acc[rr] += dot4(x4, w0);
        }
    }
#pragma unroll
    for (int rr = 0; rr < 4; ++rr) {
        acc[rr] += __shfl_xor(acc[rr], 16, 64);
        acc[rr] += __shfl_xor(acc[rr], 32, 64);
    }
    if (kc == 0) {
        float bb = b_ff[cslot];
#pragma unroll
        for (int rr = 0; rr < 4; ++rr) {
            int r = rg * 4 + rr;
            float z = acc[rr] + zp[r * SP + cslot] + bb;
            z = z > 0.f ? z : 0.01f * z;
            zs[xidx(r, cslot)] = z;
        }
    }
}

// ---- 128->128 dense, 16 waves. ----
__device__ __forceinline__ void dense128(int t0, const float* __restrict__ xls,
        const float4* __restrict__ Wp, const float* __restrict__ b,
        float* __restrict__ yg, float* __restrict__ ys) {
    int tid = threadIdx.x;
    int lane = tid & 63, w = tid >> 6;
    int kc = lane >> 3, c = lane & 7;
    int col = (w >> 3) * 64 + (w & 7) * 8 + c;
    float a0[8] = {};
#pragma unroll
    for (int j = 0; j < 4; ++j) {
        float4 w0 = Wp[(kc * 4 + j) * 128 + col];
        int off = (kc >> 1) * 36 + (kc & 1) * 16 + 4 * j;
#pragma unroll
        for (int rr = 0; rr < 8; ++rr) {
            float4 x4 = *(const float4*)(xls + rr * XR + off);
            a0[rr] += dot4(x4, w0);
        }
    }
#pragma unroll
    for (int rr = 0; rr < 8; ++rr) {
        a0[rr] += __shfl_xor(a0[rr], 8, 64);
        a0[rr] += __shfl_xor(a0[rr], 16, 64);
        a0[rr] += __shfl_xor(a0[rr], 32, 64);
    }
    if (kc == 0) {
        float bb = b[col];
#pragma unroll
        for (int rr = 0; rr < 8; ++rr) {
            float y = a0[rr] + bb;
            if (ys) ys[xidx(rr, col)] = y;
            if (yg) yg[(t0 + rr) * HH + col] = y;
        }
    }
}

// ---- stage h-half ff panel (64 KB = 4096 float4) by waves 8-15 only. ----
__device__ __forceinline__ void stage_wsh_h(const float4* __restrict__ src, float4* lds) {
    int tid2 = threadIdx.x - 512;       // 0..511 within waves 8-15
    int wv2 = tid2 >> 6;
#pragma unroll
    for (int it = 0; it < 8; ++it) {
        __builtin_amdgcn_global_load_lds(
            (const __attribute__((address_space(1))) unsigned int*)(src + it * 512 + tid2),
            (__attribute__((address_space(3))) unsigned int*)(lds + it * 512 + wv2 * 64),
            16, 0, 0);
    }
}

// ---------------- fused, barrier-free: P0 | flag1 | P1 | flag2 | P2 ----------------
__global__ __launch_bounds__(1024, 4) void mega_kernel(
        const float* __restrict__ emb, const int* __restrict__ start,
        const float4* __restrict__ win_p, const float* __restrict__ b_in,
        const float4* __restrict__ wcat,
        const float* __restrict__ b_v, const float* __restrict__ b_q,
        const float* __restrict__ b_k, const float* __restrict__ b_o,
        const float* __restrict__ w_f, const float* __restrict__ b_f,
        const float* __restrict__ w_i, const float* __restrict__ b_i,
        const float4* __restrict__ wff_p, const float* __restrict__ b_ff,
        const float4* __restrict__ wout_p, const float* __restrict__ b_out,
        float* __restrict__ k0b, float* __restrict__ v0b,
        float* __restrict__ k1b, float* __restrict__ v1b,
        float* __restrict__ g0, float* __restrict__ i0,
        float* __restrict__ g1, float* __restrict__ i1,
        const int* __restrict__ stb, unsigned* __restrict__ flags,
        float* __restrict__ out) {
    __shared__ float xs[ROWS * XR];
    __shared__ float es[ROWS * XR];
    __shared__ float hs[ROWS * XR];
    __shared__ float zs[ROWS * XR];
    __shared__ float qs[ROWS * SP];
    __shared__ float os[ROWS * SP];
    __shared__ float zp[ROWS * SP];
    __shared__ float kl[ROWS * SP];
    __shared__ float vl[ROWS * SP];
    __shared__ float gl[ROWS], il[ROWS];
    __shared__ float4 wsh[4096];  // 64 KB staged ff h-half panel
    int tid = threadIdx.x;
    int bid = blockIdx.x;
    int t0 = bid * ROWS;
    int wv = tid >> 6;

    // ---- P0 ----
    {
        int row = tid >> 7, dd = tid & 127;
        xs[row * XR + (dd >> 5) * 36 + (dd & 31)] = emb[(t0 + row) * HH + dd];
    }
    __syncthreads();
    dense128(t0, xs, win_p, b_in, (float*)0, es);
    __syncthreads();
    proj_block(t0, es, wcat, b_v, b_q, b_k, b_o, k0b, v0b, kl, vl, qs, os);
    proj_fi(t0, es, w_f, b_f, w_i, b_i, start, g0, i0, gl, il);
    __syncthreads();  // drains agent stores (vmcnt 0) + LDS kv visible
    if (tid == 0)
        __hip_atomic_store(flags + bid, 1u, __ATOMIC_RELAXED, __HIP_MEMORY_SCOPE_AGENT);

    // ---- P1: waves 0-7 attn0 | waves 8-15 stage h-panel + e-half ff0 ----
    if (wv < 8) {
        attn_row(t0, bid, 1u, flags, k0b, v0b, kl, vl, qs, os, g0, i0, gl, il, stb, hs);
    } else {
        stage_wsh_h(wff_p, wsh);
        ffe_block(es, wff_p, zp);
    }
    __syncthreads();  // drains staging (vmcnt 0) + hs/zp visible
    ffh_block(hs, wsh, zp, b_ff, zs);
    __syncthreads();
    proj_block(t0, zs, wcat + 16384, b_v + HH, b_q + HH, b_k + HH, b_o + HH,
               k1b, v1b, kl, vl, qs, os);
    proj_fi(t0, zs, w_f + HH, b_f + 1, w_i + HH, b_i + 1, start, g1, i1, gl, il);
    __syncthreads();
    if (tid == 0)
        __hip_atomic_store(flags + bid, 2u, __ATOMIC_RELAXED, __HIP_MEMORY_SCOPE_AGENT);

    // ---- P2: waves 0-7 attn1 | waves 8-15 stage + e-half ff1; then final dense ----
    if (wv < 8) {
        attn_row(t0, bid, 2u, flags, k1b, v1b, kl, vl, qs, os, g1, i1, gl, il, stb, hs);
    } else {
        stage_wsh_h(wff_p + 8192, wsh);
        ffe_block(es, wff_p + 8192, zp);
    }
    __syncthreads();
    ffh_block(hs, wsh, zp, b_ff + HH, zs);
    __syncthreads();
    dense128(t0, zs, wout_p, b_out, out, (float*)0);
}

extern "C" void kernel_launch(void* const* d_in, const int* in_sizes, int n_in,
                              void* d_out, int out_size, void* d_ws, size_t ws_size,
                              hipStream_t stream) {
    const float* emb   = (const float*)d_in[0];
    const int*   start = (const int*)  d_in[1];
    const float* w_in  = (const float*)d_in[2];
    const float* b_in  = (const float*)d_in[3];
    const float* w_out = (const float*)d_in[4];
    const float* b_out = (const float*)d_in[5];
    const float* w_f   = (const float*)d_in[6];
    const float* b_f   = (const float*)d_in[7];
    const float* w_i   = (const float*)d_in[8];
    const float* b_i   = (const float*)d_in[9];
    const float* w_v   = (const float*)d_in[10];
    const float* b_v   = (const float*)d_in[11];
    const float* w_q   = (const float*)d_in[12];
    const float* b_q   = (const float*)d_in[13];
    const float* w_k   = (const float*)d_in[14];
    const float* b_k   = (const float*)d_in[15];
    const float* w_o   = (const float*)d_in[16];
    const float* b_o   = (const float*)d_in[17];
    const float* w_ff  = (const float*)d_in[18];
    const float* b_ff  = (const float*)d_in[19];
    float* out = (float*)d_out;

    unsigned* flags = (unsigned*)d_ws;          // 256 per-block phase flags
    float* ws = (float*)d_ws + 256;
    float* k0b = ws; ws += TT * HH;
    float* v0b = ws; ws += TT * HH;
    float* k1b = ws; ws += TT * HH;
    float* v1b = ws; ws += TT * HH;
    float* g0  = ws; ws += TT;
    float* i0  = ws; ws += TT;
    float* g1  = ws; ws += TT;
    float* i1  = ws; ws += TT;
    int* stb   = (int*)ws; ws += TT;             // episode starts
    float4* win_p  = (float4*)ws; ws += 16384;   // 4096 float4
    float4* wout_p = (float4*)ws; ws += 16384;   // 4096 float4
    float4* wcat   = (float4*)ws; ws += 131072;  // 32768 float4 (2 layers)
    float4* wff_p  = (float4*)ws; ws += 65536;   // 16384 float4 (2 layers)

    prep_kernel<<<dim3(232), dim3(256), 0, stream>>>(
        w_in, w_out, w_v, w_q, w_k, w_o, w_ff, start,
        win_p, wout_p, wcat, wff_p, stb, flags);
    mega_kernel<<<dim3(NBLK), dim3(1024), 0, stream>>>(
        emb, start, win_p, b_in, wcat,
        b_v, b_q, b_k, b_o, w_f, b_f, w_i, b_i,
        wff_p, b_ff, wout_p, b_out,
        k0b, v0b, k1b, v1b, g0, i0, g1, i1,
        stb, flags, out);
}